// Round 2
// baseline (1712.054 us; speedup 1.0000x reference)
//
#include <hip/hip_runtime.h>
#include <cstdint>
#include <math.h>

typedef __bf16 bf16_t;
typedef __bf16 bf16x8 __attribute__((ext_vector_type(8)));
typedef float f32x4 __attribute__((ext_vector_type(4)));
typedef uint32_t u32x4 __attribute__((ext_vector_type(4)));
typedef uint32_t u32x2 __attribute__((ext_vector_type(2)));

#define DI __device__ __forceinline__

DI float bflo(uint32_t u){ return __builtin_bit_cast(float, (uint32_t)(u << 16)); }
DI float bfhi(uint32_t u){ return __builtin_bit_cast(float, (uint32_t)(u & 0xffff0000u)); }
DI uint16_t f2bf(float f){ bf16_t h = (bf16_t)f; return __builtin_bit_cast(uint16_t, h); }
DI uint32_t pk2(float a, float b){ return (uint32_t)f2bf(a) | ((uint32_t)f2bf(b) << 16); }
DI float geluf(float x){
  float u = 0.7978845608028654f * (x + 0.044715f * x * x * x);
  return 0.5f * x * (1.0f + tanhf(u));
}

// ---------------- weight transpose + pad + cast: Wt[Np][K] = W[k][c0+n] ----------------
__global__ __launch_bounds__(256) void wtrans_k(const float* __restrict__ W, uint16_t* __restrict__ Wt,
                                                int K, int N, int Np, int ldw, int c0)
{
  int idx = blockIdx.x * 256 + threadIdx.x;
  if (idx >= Np * K) return;
  int n = idx / K, k = idx - n * K;
  float v = (n < N) ? W[(size_t)k * ldw + c0 + n] : 0.0f;
  Wt[idx] = f2bf(v);
}

// ---------------- LayerNorm (wave per token) -> bf16 out ----------------
__global__ __launch_bounds__(256) void ln_k(const float* __restrict__ in0, const int D,
                                            const float* __restrict__ g, const float* __restrict__ bb,
                                            uint16_t* __restrict__ outp)
{
  const int token = blockIdx.x * 4 + (threadIdx.x >> 6);
  const int lane = threadIdx.x & 63;
  const float* in = in0 + (size_t)token * D;
  const int nf4 = D >> 2;
  f32x4 v[3];
  float s = 0.f, sq = 0.f;
#pragma unroll
  for (int i = 0; i < 3; ++i){
    const int c = lane + 64 * i;
    if (c < nf4){
      v[i] = *(const f32x4*)(in + 4 * c);
#pragma unroll
      for (int e = 0; e < 4; ++e){ s += v[i][e]; sq += v[i][e] * v[i][e]; }
    }
  }
#pragma unroll
  for (int off = 32; off; off >>= 1){
    s  += __shfl_xor(s, off);
    sq += __shfl_xor(sq, off);
  }
  const float mean = s / (float)D;
  const float var = sq / (float)D - mean * mean;
  const float inv = rsqrtf(var + 1e-6f);
  uint16_t* orow = outp + (size_t)token * D;
#pragma unroll
  for (int i = 0; i < 3; ++i){
    const int c = lane + 64 * i;
    if (c < nf4){
      float f0 = (v[i][0] - mean) * inv * g[4*c+0] + bb[4*c+0];
      float f1 = (v[i][1] - mean) * inv * g[4*c+1] + bb[4*c+1];
      float f2 = (v[i][2] - mean) * inv * g[4*c+2] + bb[4*c+2];
      float f3 = (v[i][3] - mean) * inv * g[4*c+3] + bb[4*c+3];
      u32x2 pk; pk[0] = pk2(f0, f1); pk[1] = pk2(f2, f3);
      *(u32x2*)(orow + 4 * c) = pk;
    }
  }
}

// ---------------- generic 128x128 bf16 MFMA GEMM, C = A(MxK) * Bt(NpxK)^T ----------------
enum { EPI_POOL = 0, EPI_BF16 = 1, EPI_GELU = 2, EPI_ADD1 = 3, EPI_ADD2 = 4 };

template<int EPI>
__global__ __launch_bounds__(256) void gemm_k(
    const uint16_t* __restrict__ A, const uint16_t* __restrict__ Bt,
    const float* __restrict__ bias, void* __restrict__ outp,
    const void* __restrict__ r1, const void* __restrict__ r2,
    const int N, const int K)
{
  __shared__ __align__(16) char smem[32768];
  uint16_t* As0 = (uint16_t*)smem;
  uint16_t* As1 = (uint16_t*)(smem + 8192);
  uint16_t* Bs0 = (uint16_t*)(smem + 16384);
  uint16_t* Bs1 = (uint16_t*)(smem + 24576);

  const int tid = threadIdx.x;
  const int lane = tid & 63;
  const int wid = tid >> 6;
  const int m0 = blockIdx.x * 128;
  const int n0 = blockIdx.y * 128;
  const int wm = (wid >> 1) * 64;
  const int wn = (wid & 1) * 64;
  const int r15 = lane & 15;
  const int kh = lane >> 4;

  const uint16_t* Abase = A + (size_t)m0 * K;
  const uint16_t* Bbase = Bt + (size_t)n0 * K;
  const int rA0 = tid >> 2, kA0 = (tid & 3) * 8;
  const int rA1 = (tid + 256) >> 2;

  u32x4 ra0, ra1, rb0, rb1;
  auto loadT = [&](int t){
    ra0 = *(const u32x4*)(Abase + (size_t)rA0 * K + t * 32 + kA0);
    ra1 = *(const u32x4*)(Abase + (size_t)rA1 * K + t * 32 + kA0);
    rb0 = *(const u32x4*)(Bbase + (size_t)rA0 * K + t * 32 + kA0);
    rb1 = *(const u32x4*)(Bbase + (size_t)rA1 * K + t * 32 + kA0);
  };
  auto storeT = [&](uint16_t* Ad, uint16_t* Bd){
    ((u32x4*)Ad)[tid] = ra0;
    ((u32x4*)Ad)[tid + 256] = ra1;
    ((u32x4*)Bd)[tid] = rb0;
    ((u32x4*)Bd)[tid + 256] = rb1;
  };

  f32x4 acc[4][4] = {};

  loadT(0);
  storeT(As0, Bs0);
  __syncthreads();
  const int nt = K >> 5;
  for (int t = 0; t < nt; ++t){
    uint16_t* Ac = (t & 1) ? As1 : As0;
    uint16_t* Bc = (t & 1) ? Bs1 : Bs0;
    if (t + 1 < nt) loadT(t + 1);
    bf16x8 af[4], bfv[4];
#pragma unroll
    for (int i = 0; i < 4; ++i)
      af[i] = *(const bf16x8*)(Ac + (wm + i * 16 + r15) * 32 + kh * 8);
#pragma unroll
    for (int j = 0; j < 4; ++j)
      bfv[j] = *(const bf16x8*)(Bc + (wn + j * 16 + r15) * 32 + kh * 8);
#pragma unroll
    for (int i = 0; i < 4; ++i)
#pragma unroll
      for (int j = 0; j < 4; ++j)
        acc[i][j] = __builtin_amdgcn_mfma_f32_16x16x32_bf16(af[i], bfv[j], acc[i][j], 0, 0, 0);
    if (t + 1 < nt) storeT((t & 1) ? As0 : As1, (t & 1) ? Bs0 : Bs1);
    __syncthreads();
  }

  if constexpr (EPI == EPI_POOL){
    // stash C tile (bf16) in LDS, then 2x2 spatial maxpool + bias.
    // M-tile = 128 tokens = 2 image rows (y0,y0+1) of one batch image (4096 tokens
    // per image, 128 | 4096). local rows 0..63 => y0, 64..127 => y0+1.
    uint16_t* Cp = (uint16_t*)smem;
#pragma unroll
    for (int i = 0; i < 4; ++i)
#pragma unroll
      for (int j = 0; j < 4; ++j)
#pragma unroll
        for (int tt = 0; tt < 4; ++tt){
          int rr = wm + i * 16 + kh * 4 + tt;
          int cc = wn + j * 16 + r15;
          Cp[rr * 128 + cc] = f2bf(acc[i][j][tt]);
        }
    __syncthreads();
    uint16_t* obp = (uint16_t*)outp;
    const int orow0 = blockIdx.x * 32;
#pragma unroll
    for (int e2 = 0; e2 < 16; ++e2){
      int idx = tid + 256 * e2;
      int X = idx >> 7, c = idx & 127;
      int gn = n0 + c;
      if (gn < N){
        float v0 = bflo(Cp[(2 * X) * 128 + c]);
        float v1 = bflo(Cp[(2 * X + 1) * 128 + c]);
        float v2 = bflo(Cp[(64 + 2 * X) * 128 + c]);
        float v3 = bflo(Cp[(65 + 2 * X) * 128 + c]);
        float v = fmaxf(fmaxf(v0, v1), fmaxf(v2, v3)) + bias[gn];
        obp[(size_t)(orow0 + X) * N + gn] = f2bf(v);
      }
    }
  } else {
    int coln[4]; float bcol[4];
#pragma unroll
    for (int j = 0; j < 4; ++j){
      coln[j] = n0 + wn + j * 16 + r15;
      bcol[j] = (coln[j] < N) ? bias[coln[j]] : 0.0f;
    }
#pragma unroll
    for (int i = 0; i < 4; ++i)
#pragma unroll
      for (int tt = 0; tt < 4; ++tt){
        const int gm = m0 + wm + i * 16 + kh * 4 + tt;
        const size_t ro = (size_t)gm * N;
#pragma unroll
        for (int j = 0; j < 4; ++j){
          if (coln[j] < N){
            float v = acc[i][j][tt] + bcol[j];
            if constexpr (EPI == EPI_BF16){
              ((uint16_t*)outp)[ro + coln[j]] = f2bf(v);
            } else if constexpr (EPI == EPI_GELU){
              ((uint16_t*)outp)[ro + coln[j]] = f2bf(geluf(v));
            } else if constexpr (EPI == EPI_ADD1){
              v += bflo(((const uint16_t*)r1)[ro + coln[j]]);
              ((float*)outp)[ro + coln[j]] = v;
            } else { // EPI_ADD2
              v += ((const float*)r1)[ro + coln[j]] + ((const float*)r2)[ro + coln[j]];
              ((float*)outp)[ro + coln[j]] = v;
            }
          }
        }
      }
  }
}

// ---------------- windowed attention (one stream): 1 wave per (window, head), lane = pooled query ----------------
__global__ __launch_bounds__(64) void attn_k(
    const uint16_t* __restrict__ qp, const uint16_t* __restrict__ kv, uint16_t* __restrict__ o)
{
  const int lane = threadIdx.x;
  const int bid = blockIdx.x;           // 0..1023
  const int h = bid & 7;
  const int w = bid >> 3;               // 0..127
  const int b = w >> 4;
  const int wy = (w >> 2) & 3;
  const int wx = w & 3;
  const int qy = lane >> 3, qx = lane & 7;
  const int prow = b * 1024 + (wy * 8 + qy) * 32 + (wx * 8 + qx);

  const u32x4* qr = (const u32x4*)(qp + (size_t)prow * 576 + h * 72);
  float q[72];
#pragma unroll
  for (int j = 0; j < 9; ++j){
    u32x4 u = qr[j];
#pragma unroll
    for (int p = 0; p < 4; ++p){
      q[j * 8 + 2 * p]     = bflo(u[p]);
      q[j * 8 + 2 * p + 1] = bfhi(u[p]);
    }
  }
  const float scale = 0.11785113019775793f;  // 1/sqrt(72)
  float m = -INFINITY, l = 0.0f;
  float oa[72] = {};
  const size_t row0 = (size_t)b * 4096 + (size_t)wy * 1024 + wx * 16;
  for (int kk = 0; kk < 256; ++kk){
    const size_t row = row0 + (size_t)(kk >> 4) * 64 + (kk & 15);
    const u32x4* kr = (const u32x4*)(kv + row * 1152 + h * 72);
    float s = 0.0f;
#pragma unroll
    for (int j = 0; j < 9; ++j){
      u32x4 u = kr[j];
#pragma unroll
      for (int p = 0; p < 4; ++p){
        s += q[j * 8 + 2 * p]     * bflo(u[p]);
        s += q[j * 8 + 2 * p + 1] * bfhi(u[p]);
      }
    }
    s *= scale;
    if (s > m){
      float f = __expf(m - s);
      l *= f;
#pragma unroll
      for (int d = 0; d < 72; ++d) oa[d] *= f;
      m = s;
    }
    float p = __expf(s - m);
    l += p;
    const u32x4* vr = (const u32x4*)(kv + row * 1152 + 576 + h * 72);
#pragma unroll
    for (int j = 0; j < 9; ++j){
      u32x4 u = vr[j];
#pragma unroll
      for (int e = 0; e < 4; ++e){
        oa[j * 8 + 2 * e]     += p * bflo(u[e]);
        oa[j * 8 + 2 * e + 1] += p * bfhi(u[e]);
      }
    }
  }
  const float inv = 1.0f / l;
  u32x4* orow = (u32x4*)(o + (size_t)prow * 576 + h * 72);
#pragma unroll
  for (int j = 0; j < 9; ++j){
    u32x4 u;
#pragma unroll
    for (int e = 0; e < 4; ++e)
      u[e] = pk2(oa[j * 8 + 2 * e] * inv, oa[j * 8 + 2 * e + 1] * inv);
    orow[j] = u;
  }
}

// ---------------- 2-expert adapter (one stream; wave per token) ----------------
__global__ __launch_bounds__(256) void adapter_k(const float* __restrict__ x2, const int si,
    const float* __restrict__ gw, const float* __restrict__ gb,
    const float* __restrict__ dw, const float* __restrict__ db,
    const float* __restrict__ uw, const float* __restrict__ ub,
    float* __restrict__ ad)
{
  __shared__ float xs[4][576];
  __shared__ float hs[4][64];
  const int wid = threadIdx.x >> 6, lane = threadIdx.x & 63;
  const int token = blockIdx.x * 4 + wid;
  const float* x = x2 + (size_t)token * 576;
  float p0 = 0.f, p1 = 0.f;
#pragma unroll
  for (int i = 0; i < 9; ++i){
    int d = lane + 64 * i;
    float xv = x[d];
    xs[wid][d] = xv;
    p0 += xv * gw[si * 1152 + d * 2];
    p1 += xv * gw[si * 1152 + d * 2 + 1];
  }
#pragma unroll
  for (int off = 32; off; off >>= 1){
    p0 += __shfl_xor(p0, off);
    p1 += __shfl_xor(p1, off);
  }
  p0 += gb[si * 2]; p1 += gb[si * 2 + 1];
  float mg = fmaxf(p0, p1);
  float e0 = __expf(p0 - mg), e1 = __expf(p1 - mg);
  float gs = e0 + e1;
  float g0 = e0 / gs, g1 = e1 / gs;
  __syncthreads();
  const int ex = lane >> 5, r = lane & 31;
  float acc = db[si * 64 + ex * 32 + r];
  const float* dwp = dw + (size_t)(si * 2 + ex) * 576 * 32 + r;
#pragma unroll 8
  for (int d = 0; d < 576; ++d) acc += xs[wid][d] * dwp[d * 32];
  hs[wid][lane] = geluf(acc);
  __syncthreads();
#pragma unroll
  for (int i = 0; i < 9; ++i){
    int d = lane + 64 * i;
    float y0 = ub[si * 1152 + d];
    float y1 = ub[si * 1152 + 576 + d];
    const float* u0 = uw + (size_t)(si * 2) * 32 * 576 + d;
    const float* u1 = uw + (size_t)(si * 2 + 1) * 32 * 576 + d;
#pragma unroll 8
    for (int rr = 0; rr < 32; ++rr){
      y0 += hs[wid][rr]      * u0[rr * 576];
      y1 += hs[wid][32 + rr] * u1[rr * 576];
    }
    ad[(size_t)token * 576 + d] = 0.5f * (g0 * y0 + g1 * y1);
  }
}

extern "C" void kernel_launch(void* const* d_in, const int* in_sizes, int n_in,
                              void* d_out, int out_size, void* d_ws, size_t ws_size,
                              hipStream_t stream)
{
  (void)in_sizes; (void)n_in; (void)out_size; (void)ws_size;
  const float* srcs[2] = { (const float*)d_in[0], (const float*)d_in[1] };  // rgb, depth
  const float* n1g    = (const float*)d_in[2];
  const float* n1b    = (const float*)d_in[3];
  const float* proj_w = (const float*)d_in[4];
  const float* proj_b = (const float*)d_in[5];
  const float* qkv_w  = (const float*)d_in[6];
  const float* qkv_b  = (const float*)d_in[7];
  const float* ap_w   = (const float*)d_in[8];
  const float* ap_b   = (const float*)d_in[9];
  const float* n2g    = (const float*)d_in[10];
  const float* n2b    = (const float*)d_in[11];
  const float* w1     = (const float*)d_in[12];
  const float* b1     = (const float*)d_in[13];
  const float* w2     = (const float*)d_in[14];
  const float* b2     = (const float*)d_in[15];
  const float* gw     = (const float*)d_in[16];
  const float* gb     = (const float*)d_in[17];
  const float* dwn    = (const float*)d_in[18];
  const float* dbn    = (const float*)d_in[19];
  const float* uw     = (const float*)d_in[20];
  const float* ub     = (const float*)d_in[21];

  char* ws = (char*)d_ws;
  size_t off = 0;
  auto alloc = [&](size_t bytes){ size_t o = off; off += (bytes + 255) & ~(size_t)255; return o; };

  // shared weights (bf16, transposed to [N_pad][K])
  uint16_t* projT = (uint16_t*)(ws + alloc((size_t)640 * 288 * 2));
  uint16_t* qT    = (uint16_t*)(ws + alloc((size_t)640 * 288 * 2));
  uint16_t* kvT   = (uint16_t*)(ws + alloc((size_t)1152 * 288 * 2));
  uint16_t* aT    = (uint16_t*)(ws + alloc((size_t)640 * 576 * 2));
  uint16_t* m1T   = (uint16_t*)(ws + alloc((size_t)2304 * 576 * 2));
  uint16_t* m2T   = (uint16_t*)(ws + alloc((size_t)640 * 2304 * 2));
  // per-stream activations (reused for si=0,1). Peak ws ~133 MiB.
  size_t oXN = alloc((size_t)32768 * 288 * 2);        // xn bf16 [32768x288]; later x2 f32 [8192x576] (same bytes)
  uint16_t* xn  = (uint16_t*)(ws + oXN);
  float*    x2  = (float*)(ws + oXN);
  uint16_t* sc  = (uint16_t*)(ws + alloc((size_t)8192 * 576 * 2));   // pooled shortcut bf16
  uint16_t* qp  = (uint16_t*)(ws + alloc((size_t)8192 * 576 * 2));   // pooled q bf16
  size_t oKV = alloc((size_t)32768 * 1152 * 2);       // kv bf16; later mlp hidden bf16 [8192x2304]
  uint16_t* kvb  = (uint16_t*)(ws + oKV);
  uint16_t* mlpH = (uint16_t*)(ws + oKV);
  size_t oR2 = alloc((size_t)8192 * 576 * 4);         // ob bf16 @0, hb bf16 @+9.4MB; later ad f32 (whole)
  uint16_t* ob = (uint16_t*)(ws + oR2);
  uint16_t* hb = (uint16_t*)(ws + oR2 + (size_t)8192 * 576 * 2);
  float*    ad = (float*)(ws + oR2);

  // weight prep (once)
  wtrans_k<<<(640 * 288 + 255) / 256, 256, 0, stream>>>(proj_w, projT, 288, 576, 640, 576, 0);
  wtrans_k<<<(640 * 288 + 255) / 256, 256, 0, stream>>>(qkv_w, qT, 288, 576, 640, 1728, 0);
  wtrans_k<<<(1152 * 288 + 255) / 256, 256, 0, stream>>>(qkv_w, kvT, 288, 1152, 1152, 1728, 576);
  wtrans_k<<<(640 * 576 + 255) / 256, 256, 0, stream>>>(ap_w, aT, 576, 576, 640, 576, 0);
  wtrans_k<<<(2304 * 576 + 255) / 256, 256, 0, stream>>>(w1, m1T, 576, 2304, 2304, 2304, 0);
  wtrans_k<<<(640 * 2304 + 255) / 256, 256, 0, stream>>>(w2, m2T, 2304, 576, 640, 576, 0);

  for (int si = 0; si < 2; ++si){
    float* outf = (float*)d_out + (size_t)si * 8192 * 576;

    // LN1 -> xn bf16 [32768 x 288]
    ln_k<<<8192, 256, 0, stream>>>(srcs[si], 288, n1g, n1b, xn);

    // proj + pooled shortcut; pooled q; k,v
    gemm_k<EPI_POOL><<<dim3(256, 5), 256, 0, stream>>>(xn, projT, proj_b, sc, nullptr, nullptr, 576, 288);
    gemm_k<EPI_POOL><<<dim3(256, 5), 256, 0, stream>>>(xn, qT, qkv_b, qp, nullptr, nullptr, 576, 288);
    gemm_k<EPI_BF16><<<dim3(256, 9), 256, 0, stream>>>(xn, kvT, qkv_b + 576, kvb, nullptr, nullptr, 1152, 288);

    // windowed attention -> ob bf16 [8192 x 576]
    attn_k<<<1024, 64, 0, stream>>>(qp, kvb, ob);

    // attn out-proj + shortcut -> x2 f32 (aliases xn, dead by now)
    gemm_k<EPI_ADD1><<<dim3(64, 5), 256, 0, stream>>>(ob, aT, ap_b, x2, sc, nullptr, 576, 576);

    // LN2 -> hb bf16
    ln_k<<<2048, 256, 0, stream>>>(x2, 576, n2g, n2b, hb);

    // MLP up + gelu -> mlpH bf16 [8192 x 2304] (aliases kv, dead by now)
    gemm_k<EPI_GELU><<<dim3(64, 18), 256, 0, stream>>>(hb, m1T, b1, mlpH, nullptr, nullptr, 2304, 576);

    // adapter (reads x2) -> ad f32 (aliases ob+hb, dead after MLP-up)
    adapter_k<<<2048, 256, 0, stream>>>(x2, si, gw, gb, dwn, dbn, uw, ub, ad);

    // MLP down + x2 + adapter -> out f32
    gemm_k<EPI_ADD2><<<dim3(64, 5), 256, 0, stream>>>(mlpH, m2T, b2, outf, x2, ad, 576, 2304);
  }
}

// Round 3
// 854.038 us; speedup vs baseline: 2.0047x; 2.0047x over previous
//
#include <hip/hip_runtime.h>
#include <cstdint>
#include <math.h>

typedef __bf16 bf16_t;
typedef __bf16 bf16x8 __attribute__((ext_vector_type(8)));
typedef float f32x4 __attribute__((ext_vector_type(4)));
typedef uint32_t u32x4 __attribute__((ext_vector_type(4)));
typedef uint32_t u32x2 __attribute__((ext_vector_type(2)));

#define DI __device__ __forceinline__

DI float bflo(uint32_t u){ return __builtin_bit_cast(float, (uint32_t)(u << 16)); }
DI float bfhi(uint32_t u){ return __builtin_bit_cast(float, (uint32_t)(u & 0xffff0000u)); }
DI uint16_t f2bf(float f){ bf16_t h = (bf16_t)f; return __builtin_bit_cast(uint16_t, h); }
DI uint32_t pk2(float a, float b){ return (uint32_t)f2bf(a) | ((uint32_t)f2bf(b) << 16); }
DI float geluf(float x){
  float u = 0.7978845608028654f * (x + 0.044715f * x * x * x);
  return 0.5f * x * (1.0f + tanhf(u));
}

#if defined(__has_builtin)
#if __has_builtin(__builtin_amdgcn_global_load_lds)
#define USE_GLLDS 1
#endif
#endif

#if USE_GLLDS
DI void gload_lds16(const void* g, void* l){
  __builtin_amdgcn_global_load_lds((__attribute__((address_space(1))) void*)g,
                                   (__attribute__((address_space(3))) void*)l, 16, 0, 0);
}
#endif

// ---------------- zero fill (u32x4 granularity) ----------------
__global__ __launch_bounds__(256) void fill0_k(u32x4* __restrict__ p, int n16)
{
  int i = blockIdx.x * 256 + threadIdx.x;
  if (i < n16){ u32x4 z = {0,0,0,0}; p[i] = z; }
}

// ---------------- weight transpose + pad + cast: Wt[Np][K] = W[k][c0+n] ----------------
__global__ __launch_bounds__(256) void wtrans_k(const float* __restrict__ W, uint16_t* __restrict__ Wt,
                                                int K, int N, int Np, int ldw, int c0)
{
  int idx = blockIdx.x * 256 + threadIdx.x;
  if (idx >= Np * K) return;
  int n = idx / K, k = idx - n * K;
  float v = (n < N) ? W[(size_t)k * ldw + c0 + n] : 0.0f;
  Wt[idx] = f2bf(v);
}

// ---------------- LayerNorm (wave per token) -> bf16 out ----------------
__global__ __launch_bounds__(256) void ln_k(const float* __restrict__ in0, const int D,
                                            const float* __restrict__ g, const float* __restrict__ bb,
                                            uint16_t* __restrict__ outp)
{
  const int token = blockIdx.x * 4 + (threadIdx.x >> 6);
  const int lane = threadIdx.x & 63;
  const float* in = in0 + (size_t)token * D;
  const int nf4 = D >> 2;
  f32x4 v[3];
  float s = 0.f, sq = 0.f;
#pragma unroll
  for (int i = 0; i < 3; ++i){
    const int c = lane + 64 * i;
    if (c < nf4){
      v[i] = *(const f32x4*)(in + 4 * c);
#pragma unroll
      for (int e = 0; e < 4; ++e){ s += v[i][e]; sq += v[i][e] * v[i][e]; }
    }
  }
#pragma unroll
  for (int off = 32; off; off >>= 1){
    s  += __shfl_xor(s, off);
    sq += __shfl_xor(sq, off);
  }
  const float mean = s / (float)D;
  const float var = sq / (float)D - mean * mean;
  const float inv = rsqrtf(var + 1e-6f);
  uint16_t* orow = outp + (size_t)token * D;
#pragma unroll
  for (int i = 0; i < 3; ++i){
    const int c = lane + 64 * i;
    if (c < nf4){
      float f0 = (v[i][0] - mean) * inv * g[4*c+0] + bb[4*c+0];
      float f1 = (v[i][1] - mean) * inv * g[4*c+1] + bb[4*c+1];
      float f2 = (v[i][2] - mean) * inv * g[4*c+2] + bb[4*c+2];
      float f3 = (v[i][3] - mean) * inv * g[4*c+3] + bb[4*c+3];
      u32x2 pk; pk[0] = pk2(f0, f1); pk[1] = pk2(f2, f3);
      *(u32x2*)(orow + 4 * c) = pk;
    }
  }
}

// ---------------- generic 128x128 bf16 MFMA GEMM, C = A(MxK) * Bt(NpxK)^T ----------------
enum { EPI_POOL = 0, EPI_KV = 1, EPI_GELU = 2, EPI_ADD1 = 3, EPI_ADD2 = 4 };

template<int EPI>
__global__ __launch_bounds__(256) void gemm_k(
    const uint16_t* __restrict__ A, const uint16_t* __restrict__ Bt,
    const float* __restrict__ bias, void* __restrict__ outp,
    const void* __restrict__ r1, const void* __restrict__ r2,
    const int N, const int K)
{
  __shared__ __align__(16) char smem[32768];
  uint16_t* As0 = (uint16_t*)smem;
  uint16_t* As1 = (uint16_t*)(smem + 8192);
  uint16_t* Bs0 = (uint16_t*)(smem + 16384);
  uint16_t* Bs1 = (uint16_t*)(smem + 24576);

  const int tid = threadIdx.x;
  const int lane = tid & 63;
  const int wid = tid >> 6;
  const int m0 = blockIdx.x * 128;
  const int n0 = blockIdx.y * 128;
  const int wm = (wid >> 1) * 64;
  const int wn = (wid & 1) * 64;
  const int r15 = lane & 15;
  const int kh = lane >> 4;

  const uint16_t* Abase = A + (size_t)m0 * K;
  const uint16_t* Bbase = Bt + (size_t)n0 * K;
  const int rA0 = tid >> 2, kA0 = (tid & 3) * 8;
  const int rA1 = (tid + 256) >> 2;

  auto stage = [&](uint16_t* Ad, uint16_t* Bd, int t){
    const uint16_t* ga0 = Abase + (size_t)rA0 * K + t * 32 + kA0;
    const uint16_t* ga1 = Abase + (size_t)rA1 * K + t * 32 + kA0;
    const uint16_t* gb0 = Bbase + (size_t)rA0 * K + t * 32 + kA0;
    const uint16_t* gb1 = Bbase + (size_t)rA1 * K + t * 32 + kA0;
#if USE_GLLDS
    gload_lds16(ga0, Ad + (size_t)tid * 8);
    gload_lds16(ga1, Ad + (size_t)(tid + 256) * 8);
    gload_lds16(gb0, Bd + (size_t)tid * 8);
    gload_lds16(gb1, Bd + (size_t)(tid + 256) * 8);
#else
    ((u32x4*)Ad)[tid]       = *(const u32x4*)ga0;
    ((u32x4*)Ad)[tid + 256] = *(const u32x4*)ga1;
    ((u32x4*)Bd)[tid]       = *(const u32x4*)gb0;
    ((u32x4*)Bd)[tid + 256] = *(const u32x4*)gb1;
#endif
  };

  f32x4 acc[4][4] = {};

  stage(As0, Bs0, 0);
  __syncthreads();
  const int nt = K >> 5;
  for (int t = 0; t < nt; ++t){
    uint16_t* Ac = (t & 1) ? As1 : As0;
    uint16_t* Bc = (t & 1) ? Bs1 : Bs0;
    if (t + 1 < nt) stage((t & 1) ? As0 : As1, (t & 1) ? Bs0 : Bs1, t + 1);
    bf16x8 af[4], bfv[4];
#pragma unroll
    for (int i = 0; i < 4; ++i)
      af[i] = *(const bf16x8*)(Ac + (wm + i * 16 + r15) * 32 + kh * 8);
#pragma unroll
    for (int j = 0; j < 4; ++j)
      bfv[j] = *(const bf16x8*)(Bc + (wn + j * 16 + r15) * 32 + kh * 8);
#pragma unroll
    for (int i = 0; i < 4; ++i)
#pragma unroll
      for (int j = 0; j < 4; ++j)
        acc[i][j] = __builtin_amdgcn_mfma_f32_16x16x32_bf16(af[i], bfv[j], acc[i][j], 0, 0, 0);
    __syncthreads();
  }

  if constexpr (EPI == EPI_POOL){
    // stash C tile (bf16) in LDS, then 2x2 spatial maxpool + bias.
    uint16_t* Cp = (uint16_t*)smem;
#pragma unroll
    for (int i = 0; i < 4; ++i)
#pragma unroll
      for (int j = 0; j < 4; ++j)
#pragma unroll
        for (int tt = 0; tt < 4; ++tt){
          int rr = wm + i * 16 + kh * 4 + tt;
          int cc = wn + j * 16 + r15;
          Cp[rr * 128 + cc] = f2bf(acc[i][j][tt]);
        }
    __syncthreads();
    uint16_t* obp = (uint16_t*)outp;
    const int orow0 = blockIdx.x * 32;
#pragma unroll
    for (int e2 = 0; e2 < 16; ++e2){
      int idx = tid + 256 * e2;
      int X = idx >> 7, c = idx & 127;
      int gn = n0 + c;
      if (gn < N){
        float v0 = bflo(Cp[(2 * X) * 128 + c]);
        float v1 = bflo(Cp[(2 * X + 1) * 128 + c]);
        float v2 = bflo(Cp[(64 + 2 * X) * 128 + c]);
        float v3 = bflo(Cp[(65 + 2 * X) * 128 + c]);
        float v = fmaxf(fmaxf(v0, v1), fmaxf(v2, v3)) + bias[gn];
        obp[(size_t)(orow0 + X) * N + gn] = f2bf(v);
      }
    }
  } else {
    int coln[4]; float bcol[4];
#pragma unroll
    for (int j = 0; j < 4; ++j){
      coln[j] = n0 + wn + j * 16 + r15;
      bcol[j] = (coln[j] < N) ? bias[coln[j]] : 0.0f;
    }
#pragma unroll
    for (int i = 0; i < 4; ++i)
#pragma unroll
      for (int tt = 0; tt < 4; ++tt){
        const int gm = m0 + wm + i * 16 + kh * 4 + tt;
        const size_t ro = (size_t)gm * N;
#pragma unroll
        for (int j = 0; j < 4; ++j){
          if (coln[j] < N){
            float v = acc[i][j][tt] + bcol[j];
            if constexpr (EPI == EPI_KV){
              // n<576: K -> kb[token][576]. n>=576: V -> vt[wh][80][256] transposed.
              int n = coln[j];
              if (n < 576){
                ((uint16_t*)outp)[(size_t)gm * 576 + n] = f2bf(v);
              } else {
                int d = n - 576;
                int hh = d / 72, dd = d - hh * 72;
                int bimg = gm >> 12, y = (gm >> 6) & 63, x = gm & 63;
                int w = bimg * 16 + (y >> 4) * 4 + (x >> 4);
                int kl = (y & 15) * 16 + (x & 15);
                ((uint16_t*)r1)[((size_t)(w * 8 + hh) * 80 + dd) * 256 + kl] = f2bf(v);
              }
            } else if constexpr (EPI == EPI_GELU){
              ((uint16_t*)outp)[ro + coln[j]] = f2bf(geluf(v));
            } else if constexpr (EPI == EPI_ADD1){
              v += bflo(((const uint16_t*)r1)[ro + coln[j]]);
              ((float*)outp)[ro + coln[j]] = v;
            } else { // EPI_ADD2
              v += ((const float*)r1)[ro + coln[j]] + ((const float*)r2)[ro + coln[j]];
              ((float*)outp)[ro + coln[j]] = v;
            }
          }
        }
      }
  }
}

// ---------------- MFMA windowed attention: 1 wave per (window, head) ----------------
// S^T = mfma(K_frag, Q_frag): S^T[key=kh*4+tt][q=r15]; PV via custom in-lane slot map.
__global__ __launch_bounds__(64, 1) void attn_mfma_k(
    const uint16_t* __restrict__ qp,   // [8192][576] pooled q (unscaled)
    const uint16_t* __restrict__ kb,   // [32768][576] K
    const uint16_t* __restrict__ vt,   // [1024][80][256] V^T per (window,head), rows 72..79 zero
    uint16_t* __restrict__ o)          // [8192][576]
{
  const int lane = threadIdx.x;
  const int r15 = lane & 15;
  const int kh = lane >> 4;
  const int bid = blockIdx.x;          // 0..1023
  const int h = bid & 7;
  const int w = bid >> 3;
  const int b = w >> 4;
  const int wy = (w >> 2) & 3;
  const int wx = w & 3;

  const u32x4 ZU = {0, 0, 0, 0};
  const bf16x8 Z8 = __builtin_bit_cast(bf16x8, ZU);
  const float scale = 0.11785113019775793f;  // 1/sqrt(72)

  // Q fragments (B-operand): q = j*16 + r15, dims s*32 + kh*8 (s=2: kh==0 only)
  bf16x8 qf[4][3];
  int qrow[4];
#pragma unroll
  for (int j = 0; j < 4; ++j){
    int q = j * 16 + r15;
    int y = wy * 8 + (q >> 3), x = wx * 8 + (q & 7);
    qrow[j] = b * 1024 + y * 32 + x;
    const uint16_t* qpr = qp + (size_t)qrow[j] * 576 + h * 72;
    qf[j][0] = *(const bf16x8*)(qpr + kh * 8);
    qf[j][1] = *(const bf16x8*)(qpr + 32 + kh * 8);
    qf[j][2] = (kh == 0) ? *(const bf16x8*)(qpr + 64) : Z8;
  }

  float m[4], l[4];
#pragma unroll
  for (int j = 0; j < 4; ++j){ m[j] = -INFINITY; l[j] = 0.0f; }
  f32x4 acco[5][4] = {};   // [d-tile][q-tile]: O^T[d=i2*16+kh*4+tt][q=j*16+r15]
  const size_t vtbase = (size_t)(w * 8 + h) * 80 * 256;

  for (int t = 0; t < 4; ++t){
    // ---- QK^T for 64 keys ----
    f32x4 accs[4][4] = {};
#pragma unroll
    for (int i = 0; i < 4; ++i){
      const uint16_t* kr = kb + (size_t)(b * 4096 + (wy * 16 + t * 4 + i) * 64 + wx * 16 + r15) * 576 + h * 72;
      bf16x8 kf0 = *(const bf16x8*)(kr + kh * 8);
      bf16x8 kf1 = *(const bf16x8*)(kr + 32 + kh * 8);
      bf16x8 kf2 = (kh == 0) ? *(const bf16x8*)(kr + 64) : Z8;
#pragma unroll
      for (int j = 0; j < 4; ++j){
        accs[i][j] = __builtin_amdgcn_mfma_f32_16x16x32_bf16(kf0, qf[j][0], accs[i][j], 0, 0, 0);
        accs[i][j] = __builtin_amdgcn_mfma_f32_16x16x32_bf16(kf1, qf[j][1], accs[i][j], 0, 0, 0);
        accs[i][j] = __builtin_amdgcn_mfma_f32_16x16x32_bf16(kf2, qf[j][2], accs[i][j], 0, 0, 0);
      }
    }
    // ---- online softmax (per j: 4 queries per lane-col) ----
#pragma unroll
    for (int j = 0; j < 4; ++j){
      float mx = -INFINITY;
#pragma unroll
      for (int i = 0; i < 4; ++i)
#pragma unroll
        for (int tt = 0; tt < 4; ++tt){
          float sv = accs[i][j][tt] * scale;
          accs[i][j][tt] = sv;
          mx = fmaxf(mx, sv);
        }
      mx = fmaxf(mx, __shfl_xor(mx, 16));
      mx = fmaxf(mx, __shfl_xor(mx, 32));
      float nm = fmaxf(m[j], mx);
      float f = __expf(m[j] - nm);
      m[j] = nm;
      l[j] *= f;
#pragma unroll
      for (int i2 = 0; i2 < 5; ++i2) acco[i2][j] *= f;
      float ls = 0.0f;
#pragma unroll
      for (int i = 0; i < 4; ++i)
#pragma unroll
        for (int tt = 0; tt < 4; ++tt){
          float p = __expf(accs[i][j][tt] - nm);
          accs[i][j][tt] = p;
          ls += p;
        }
      ls += __shfl_xor(ls, 16);
      ls += __shfl_xor(ls, 32);
      l[j] += ls;
    }
    // ---- pack P to bf16 (in-lane) ----
    uint32_t pw[4][4][2];
#pragma unroll
    for (int i = 0; i < 4; ++i)
#pragma unroll
      for (int j = 0; j < 4; ++j){
        pw[i][j][0] = pk2(accs[i][j][0], accs[i][j][1]);
        pw[i][j][1] = pk2(accs[i][j][2], accs[i][j][3]);
      }
    // ---- PV: O^T += V^T_frag x P_frag (custom slot map, zero shuffles) ----
#pragma unroll
    for (int ks = 0; ks < 2; ++ks){
      bf16x8 pb[4];
#pragma unroll
      for (int j = 0; j < 4; ++j){
        u32x4 u = {pw[2 * ks][j][0], pw[2 * ks][j][1], pw[2 * ks + 1][j][0], pw[2 * ks + 1][j][1]};
        pb[j] = __builtin_bit_cast(bf16x8, u);
      }
#pragma unroll
      for (int i2 = 0; i2 < 5; ++i2){
        const uint16_t* vr = vt + vtbase + (size_t)(i2 * 16 + r15) * 256 + t * 64 + ks * 32 + kh * 4;
        u32x2 lo = *(const u32x2*)(vr);
        u32x2 hi = *(const u32x2*)(vr + 16);
        u32x4 av = {lo[0], lo[1], hi[0], hi[1]};
        bf16x8 va = __builtin_bit_cast(bf16x8, av);
#pragma unroll
        for (int j = 0; j < 4; ++j)
          acco[i2][j] = __builtin_amdgcn_mfma_f32_16x16x32_bf16(va, pb[j], acco[i2][j], 0, 0, 0);
      }
    }
  }

  // ---- write O (divide by l; l is in-lane per j) ----
#pragma unroll
  for (int j = 0; j < 4; ++j){
    float inv = 1.0f / l[j];
    uint16_t* orow = o + (size_t)qrow[j] * 576 + h * 72;
#pragma unroll
    for (int i2 = 0; i2 < 5; ++i2)
#pragma unroll
      for (int tt = 0; tt < 4; ++tt){
        int d = i2 * 16 + kh * 4 + tt;
        if (d < 72) orow[d] = f2bf(acco[i2][j][tt] * inv);
      }
  }
}

// ---------------- 2-expert adapter (one stream; wave per token) ----------------
__global__ __launch_bounds__(256) void adapter_k(const float* __restrict__ x2, const int si,
    const float* __restrict__ gw, const float* __restrict__ gb,
    const float* __restrict__ dw, const float* __restrict__ db,
    const float* __restrict__ uw, const float* __restrict__ ub,
    float* __restrict__ ad)
{
  __shared__ float xs[4][576];
  __shared__ float hs[4][64];
  const int wid = threadIdx.x >> 6, lane = threadIdx.x & 63;
  const int token = blockIdx.x * 4 + wid;
  const float* x = x2 + (size_t)token * 576;
  float p0 = 0.f, p1 = 0.f;
#pragma unroll
  for (int i = 0; i < 9; ++i){
    int d = lane + 64 * i;
    float xv = x[d];
    xs[wid][d] = xv;
    p0 += xv * gw[si * 1152 + d * 2];
    p1 += xv * gw[si * 1152 + d * 2 + 1];
  }
#pragma unroll
  for (int off = 32; off; off >>= 1){
    p0 += __shfl_xor(p0, off);
    p1 += __shfl_xor(p1, off);
  }
  p0 += gb[si * 2]; p1 += gb[si * 2 + 1];
  float mg = fmaxf(p0, p1);
  float e0 = __expf(p0 - mg), e1 = __expf(p1 - mg);
  float gs = e0 + e1;
  float g0 = e0 / gs, g1 = e1 / gs;
  __syncthreads();
  const int ex = lane >> 5, r = lane & 31;
  float acc = db[si * 64 + ex * 32 + r];
  const float* dwp = dw + (size_t)(si * 2 + ex) * 576 * 32 + r;
#pragma unroll 8
  for (int d = 0; d < 576; ++d) acc += xs[wid][d] * dwp[d * 32];
  hs[wid][lane] = geluf(acc);
  __syncthreads();
#pragma unroll
  for (int i = 0; i < 9; ++i){
    int d = lane + 64 * i;
    float y0 = ub[si * 1152 + d];
    float y1 = ub[si * 1152 + 576 + d];
    const float* u0 = uw + (size_t)(si * 2) * 32 * 576 + d;
    const float* u1 = uw + (size_t)(si * 2 + 1) * 32 * 576 + d;
#pragma unroll 8
    for (int rr = 0; rr < 32; ++rr){
      y0 += hs[wid][rr]      * u0[rr * 576];
      y1 += hs[wid][32 + rr] * u1[rr * 576];
    }
    ad[(size_t)token * 576 + d] = 0.5f * (g0 * y0 + g1 * y1);
  }
}

extern "C" void kernel_launch(void* const* d_in, const int* in_sizes, int n_in,
                              void* d_out, int out_size, void* d_ws, size_t ws_size,
                              hipStream_t stream)
{
  (void)in_sizes; (void)n_in; (void)out_size; (void)ws_size;
  const float* srcs[2] = { (const float*)d_in[0], (const float*)d_in[1] };
  const float* n1g    = (const float*)d_in[2];
  const float* n1b    = (const float*)d_in[3];
  const float* proj_w = (const float*)d_in[4];
  const float* proj_b = (const float*)d_in[5];
  const float* qkv_w  = (const float*)d_in[6];
  const float* qkv_b  = (const float*)d_in[7];
  const float* ap_w   = (const float*)d_in[8];
  const float* ap_b   = (const float*)d_in[9];
  const float* n2g    = (const float*)d_in[10];
  const float* n2b    = (const float*)d_in[11];
  const float* w1     = (const float*)d_in[12];
  const float* b1     = (const float*)d_in[13];
  const float* w2     = (const float*)d_in[14];
  const float* b2     = (const float*)d_in[15];
  const float* gw     = (const float*)d_in[16];
  const float* gb     = (const float*)d_in[17];
  const float* dwn    = (const float*)d_in[18];
  const float* dbn    = (const float*)d_in[19];
  const float* uw     = (const float*)d_in[20];
  const float* ub     = (const float*)d_in[21];

  char* ws = (char*)d_ws;
  size_t off = 0;
  auto alloc = [&](size_t bytes){ size_t o = off; off += (bytes + 255) & ~(size_t)255; return o; };

  // shared weights (bf16, transposed to [N_pad][K])
  uint16_t* projT = (uint16_t*)(ws + alloc((size_t)640 * 288 * 2));
  uint16_t* qT    = (uint16_t*)(ws + alloc((size_t)640 * 288 * 2));
  uint16_t* kvT   = (uint16_t*)(ws + alloc((size_t)1152 * 288 * 2));
  uint16_t* aT    = (uint16_t*)(ws + alloc((size_t)640 * 576 * 2));
  uint16_t* m1T   = (uint16_t*)(ws + alloc((size_t)2304 * 576 * 2));
  uint16_t* m2T   = (uint16_t*)(ws + alloc((size_t)640 * 2304 * 2));
  // per-stream activations (reused for si=0,1). Peak ws ~144 MiB.
  size_t oXN = alloc((size_t)32768 * 288 * 2);       // xn bf16; later x2 f32 (same bytes)
  uint16_t* xn  = (uint16_t*)(ws + oXN);
  float*    x2  = (float*)(ws + oXN);
  uint16_t* sc  = (uint16_t*)(ws + alloc((size_t)8192 * 576 * 2));   // pooled shortcut bf16
  uint16_t* qp  = (uint16_t*)(ws + alloc((size_t)8192 * 576 * 2));   // pooled q bf16
  uint16_t* kb  = (uint16_t*)(ws + alloc((size_t)32768 * 576 * 2));  // K bf16 [32768][576]
  size_t oVT = alloc((size_t)1024 * 80 * 256 * 2);   // V^T bf16 [1024 wh][80][256]; later mlpH [8192][2304]
  uint16_t* vt   = (uint16_t*)(ws + oVT);
  uint16_t* mlpH = (uint16_t*)(ws + oVT);
  size_t oR2 = alloc((size_t)8192 * 576 * 4);        // ob bf16 @0, hb bf16 @+9.4MB; later ad f32
  uint16_t* ob = (uint16_t*)(ws + oR2);
  uint16_t* hb = (uint16_t*)(ws + oR2 + (size_t)8192 * 576 * 2);
  float*    ad = (float*)(ws + oR2);

  // weight prep (once)
  wtrans_k<<<(640 * 288 + 255) / 256, 256, 0, stream>>>(proj_w, projT, 288, 576, 640, 576, 0);
  wtrans_k<<<(640 * 288 + 255) / 256, 256, 0, stream>>>(qkv_w, qT, 288, 576, 640, 1728, 0);
  wtrans_k<<<(1152 * 288 + 255) / 256, 256, 0, stream>>>(qkv_w, kvT, 288, 1152, 1152, 1728, 576);
  wtrans_k<<<(640 * 576 + 255) / 256, 256, 0, stream>>>(ap_w, aT, 576, 576, 640, 576, 0);
  wtrans_k<<<(2304 * 576 + 255) / 256, 256, 0, stream>>>(w1, m1T, 576, 2304, 2304, 2304, 0);
  wtrans_k<<<(640 * 2304 + 255) / 256, 256, 0, stream>>>(w2, m2T, 2304, 576, 640, 576, 0);

  const int vt_n16 = (1024 * 80 * 256 * 2) / 16;

  for (int si = 0; si < 2; ++si){
    float* outf = (float*)d_out + (size_t)si * 8192 * 576;

    // LN1 -> xn bf16 [32768 x 288]
    ln_k<<<8192, 256, 0, stream>>>(srcs[si], 288, n1g, n1b, xn);

    // zero V^T (pad rows must be 0; mlpH aliased it last stream)
    fill0_k<<<(vt_n16 + 255) / 256, 256, 0, stream>>>((u32x4*)vt, vt_n16);

    // proj + pooled shortcut; pooled q; k,v (K compact + V^T scatter)
    gemm_k<EPI_POOL><<<dim3(256, 5), 256, 0, stream>>>(xn, projT, proj_b, sc, nullptr, nullptr, 576, 288);
    gemm_k<EPI_POOL><<<dim3(256, 5), 256, 0, stream>>>(xn, qT, qkv_b, qp, nullptr, nullptr, 576, 288);
    gemm_k<EPI_KV><<<dim3(256, 9), 256, 0, stream>>>(xn, kvT, qkv_b + 576, kb, vt, nullptr, 1152, 288);

    // MFMA windowed attention -> ob bf16 [8192 x 576]
    attn_mfma_k<<<1024, 64, 0, stream>>>(qp, kb, vt, ob);

    // attn out-proj + shortcut -> x2 f32 (aliases xn, dead by now)
    gemm_k<EPI_ADD1><<<dim3(64, 5), 256, 0, stream>>>(ob, aT, ap_b, x2, sc, nullptr, 576, 576);

    // LN2 -> hb bf16
    ln_k<<<2048, 256, 0, stream>>>(x2, 576, n2g, n2b, hb);

    // MLP up + gelu -> mlpH bf16 [8192 x 2304] (aliases vt, dead after attn)
    gemm_k<EPI_GELU><<<dim3(64, 18), 256, 0, stream>>>(hb, m1T, b1, mlpH, nullptr, nullptr, 2304, 576);

    // adapter (reads x2) -> ad f32 (aliases ob+hb, dead after MLP-up)
    adapter_k<<<2048, 256, 0, stream>>>(x2, si, gw, gb, dwn, dbn, uw, ub, ad);

    // MLP down + x2 + adapter -> out f32
    gemm_k<EPI_ADD2><<<dim3(64, 5), 256, 0, stream>>>(mlpH, m2T, b2, outf, x2, ad, 576, 2304);
  }
}

// Round 4
// 760.340 us; speedup vs baseline: 2.2517x; 1.1232x over previous
//
#include <hip/hip_runtime.h>
#include <cstdint>
#include <math.h>

typedef __bf16 bf16_t;
typedef __bf16 bf16x8 __attribute__((ext_vector_type(8)));
typedef float f32x4 __attribute__((ext_vector_type(4)));
typedef uint32_t u32x4 __attribute__((ext_vector_type(4)));
typedef uint32_t u32x2 __attribute__((ext_vector_type(2)));

#define DI __device__ __forceinline__

DI float bflo(uint32_t u){ return __builtin_bit_cast(float, (uint32_t)(u << 16)); }
DI float bfhi(uint32_t u){ return __builtin_bit_cast(float, (uint32_t)(u & 0xffff0000u)); }
DI uint16_t f2bf(float f){ bf16_t h = (bf16_t)f; return __builtin_bit_cast(uint16_t, h); }
DI uint32_t pk2(float a, float b){ return (uint32_t)f2bf(a) | ((uint32_t)f2bf(b) << 16); }
DI float geluf(float x){
  float u = 0.7978845608028654f * (x + 0.044715f * x * x * x);
  return 0.5f * x * (1.0f + tanhf(u));
}

#if defined(__has_builtin)
#if __has_builtin(__builtin_amdgcn_global_load_lds)
#define USE_GLLDS 1
#endif
#endif

#if USE_GLLDS
DI void gload_lds16(const void* g, void* l){
  __builtin_amdgcn_global_load_lds((__attribute__((address_space(1))) void*)g,
                                   (__attribute__((address_space(3))) void*)l, 16, 0, 0);
}
#endif

// ---------------- zero V^T pad rows (rows 72..79 of each [80][256] slab) ----------------
__global__ __launch_bounds__(256) void vtpad_k(uint16_t* __restrict__ vt)
{
  int idx = blockIdx.x * 256 + threadIdx.x;          // < 1024*8*256
  int wh = idx >> 11, r = (idx >> 8) & 7, c = idx & 255;
  vt[((size_t)(wh * 80 + 72 + r)) * 256 + c] = 0;
}

// ---------------- weight transpose + pad + cast: Wt[Np][K] = W[k][c0+n] ----------------
__global__ __launch_bounds__(256) void wtrans_k(const float* __restrict__ W, uint16_t* __restrict__ Wt,
                                                int K, int N, int Np, int ldw, int c0)
{
  int idx = blockIdx.x * 256 + threadIdx.x;
  if (idx >= Np * K) return;
  int n = idx / K, k = idx - n * K;
  float v = (n < N) ? W[(size_t)k * ldw + c0 + n] : 0.0f;
  Wt[idx] = f2bf(v);
}

// ---------------- build extended MLP-down weight: m2Te[si][640][2400] ----------------
__global__ __launch_bounds__(256) void mk_m2te_k(const float* __restrict__ w2,
    const float* __restrict__ uw, const float* __restrict__ ub, uint16_t* __restrict__ m2Te)
{
  int idx = blockIdx.x * 256 + threadIdx.x;
  if (idx >= 2 * 640 * 2400) return;
  int si = idx / (640 * 2400);
  int rem = idx - si * 640 * 2400;
  int n = rem / 2400, k = rem - n * 2400;
  float v = 0.0f;
  if (n < 576){
    if (k < 2304) v = w2[(size_t)k * 576 + n];
    else if (k < 2368){
      int e = (k - 2304) >> 5, r = (k - 2304) & 31;
      v = uw[((size_t)(si * 2 + e) * 32 + r) * 576 + n];
    } else if (k < 2370){
      v = ub[(size_t)(si * 2 + (k - 2368)) * 576 + n];
    }
  }
  m2Te[idx] = f2bf(v);
}

// ---------------- build adapter phase-1 weight adT[si][128][576] + bias adB[si][128] ----------------
__global__ __launch_bounds__(256) void mk_adt_k(const float* __restrict__ dwn, const float* __restrict__ gw,
    const float* __restrict__ dbn, const float* __restrict__ gb,
    uint16_t* __restrict__ adT, float* __restrict__ adB)
{
  int idx = blockIdx.x * 256 + threadIdx.x;
  if (idx >= 2 * 128 * 576) return;
  int si = idx / (128 * 576);
  int rem = idx - si * 128 * 576;
  int n = rem / 576, k = rem - n * 576;
  float v = 0.0f;
  if (n < 64){
    int e = n >> 5, r = n & 31;
    v = dwn[((size_t)(si * 2 + e) * 576 + k) * 32 + r];
  } else if (n < 66){
    v = gw[(size_t)si * 1152 + k * 2 + (n - 64)];
  }
  adT[idx] = f2bf(v);
  if (k == 0){
    float bv = 0.0f;
    if (n < 64) bv = dbn[si * 64 + (n >> 5) * 32 + (n & 31)];
    else if (n < 66) bv = gb[si * 2 + (n - 64)];
    adB[si * 128 + n] = bv;
  }
}

// ---------------- LayerNorm (wave per token) -> bf16 out ----------------
__global__ __launch_bounds__(256) void ln_k(const float* __restrict__ in0, const int D,
                                            const float* __restrict__ g, const float* __restrict__ bb,
                                            uint16_t* __restrict__ outp)
{
  const int token = blockIdx.x * 4 + (threadIdx.x >> 6);
  const int lane = threadIdx.x & 63;
  const float* in = in0 + (size_t)token * D;
  const int nf4 = D >> 2;
  f32x4 v[3];
  float s = 0.f, sq = 0.f;
#pragma unroll
  for (int i = 0; i < 3; ++i){
    const int c = lane + 64 * i;
    if (c < nf4){
      v[i] = *(const f32x4*)(in + 4 * c);
#pragma unroll
      for (int e = 0; e < 4; ++e){ s += v[i][e]; sq += v[i][e] * v[i][e]; }
    }
  }
#pragma unroll
  for (int off = 32; off; off >>= 1){
    s  += __shfl_xor(s, off);
    sq += __shfl_xor(sq, off);
  }
  const float mean = s / (float)D;
  const float var = sq / (float)D - mean * mean;
  const float inv = rsqrtf(var + 1e-6f);
  uint16_t* orow = outp + (size_t)token * D;
#pragma unroll
  for (int i = 0; i < 3; ++i){
    const int c = lane + 64 * i;
    if (c < nf4){
      float f0 = (v[i][0] - mean) * inv * g[4*c+0] + bb[4*c+0];
      float f1 = (v[i][1] - mean) * inv * g[4*c+1] + bb[4*c+1];
      float f2 = (v[i][2] - mean) * inv * g[4*c+2] + bb[4*c+2];
      float f3 = (v[i][3] - mean) * inv * g[4*c+3] + bb[4*c+3];
      u32x2 pk; pk[0] = pk2(f0, f1); pk[1] = pk2(f2, f3);
      *(u32x2*)(orow + 4 * c) = pk;
    }
  }
}

// ---------------- generic 128x128 bf16 MFMA GEMM, C = A(MxK) * Bt(NpxK)^T ----------------
enum { EPI_POOL = 0, EPI_KV = 1, EPI_GELU = 2, EPI_ADD1 = 3, EPI_ADDF = 4, EPI_ADPT = 5 };

template<int EPI>
__global__ __launch_bounds__(256) void gemm_k(
    const uint16_t* __restrict__ A, const uint16_t* __restrict__ Bt,
    const float* __restrict__ bias, void* __restrict__ outp,
    void* __restrict__ r1, void* __restrict__ r2,
    const int N, const int K, const int ldo)
{
  __shared__ __align__(16) char smem[32768];
  uint16_t* As0 = (uint16_t*)smem;
  uint16_t* As1 = (uint16_t*)(smem + 8192);
  uint16_t* Bs0 = (uint16_t*)(smem + 16384);
  uint16_t* Bs1 = (uint16_t*)(smem + 24576);

  const int tid = threadIdx.x;
  const int lane = tid & 63;
  const int wid = tid >> 6;
  const int m0 = blockIdx.x * 128;
  const int n0 = blockIdx.y * 128;
  const int wm = (wid >> 1) * 64;
  const int wn = (wid & 1) * 64;
  const int r15 = lane & 15;
  const int kh = lane >> 4;

  const uint16_t* Abase = A + (size_t)m0 * K;
  const uint16_t* Bbase = Bt + (size_t)n0 * K;
  const int rA0 = tid >> 2, kA0 = (tid & 3) * 8;
  const int rA1 = (tid + 256) >> 2;

  auto stage = [&](uint16_t* Ad, uint16_t* Bd, int t){
    const uint16_t* ga0 = Abase + (size_t)rA0 * K + t * 32 + kA0;
    const uint16_t* ga1 = Abase + (size_t)rA1 * K + t * 32 + kA0;
    const uint16_t* gb0 = Bbase + (size_t)rA0 * K + t * 32 + kA0;
    const uint16_t* gb1 = Bbase + (size_t)rA1 * K + t * 32 + kA0;
#if USE_GLLDS
    gload_lds16(ga0, Ad + (size_t)tid * 8);
    gload_lds16(ga1, Ad + (size_t)(tid + 256) * 8);
    gload_lds16(gb0, Bd + (size_t)tid * 8);
    gload_lds16(gb1, Bd + (size_t)(tid + 256) * 8);
#else
    ((u32x4*)Ad)[tid]       = *(const u32x4*)ga0;
    ((u32x4*)Ad)[tid + 256] = *(const u32x4*)ga1;
    ((u32x4*)Bd)[tid]       = *(const u32x4*)gb0;
    ((u32x4*)Bd)[tid + 256] = *(const u32x4*)gb1;
#endif
  };

  f32x4 acc[4][4] = {};

  stage(As0, Bs0, 0);
  __syncthreads();
  const int nt = K >> 5;
  for (int t = 0; t < nt; ++t){
    uint16_t* Ac = (t & 1) ? As1 : As0;
    uint16_t* Bc = (t & 1) ? Bs1 : Bs0;
    if (t + 1 < nt) stage((t & 1) ? As0 : As1, (t & 1) ? Bs0 : Bs1, t + 1);
    bf16x8 af[4], bfv[4];
#pragma unroll
    for (int i = 0; i < 4; ++i)
      af[i] = *(const bf16x8*)(Ac + (wm + i * 16 + r15) * 32 + kh * 8);
#pragma unroll
    for (int j = 0; j < 4; ++j)
      bfv[j] = *(const bf16x8*)(Bc + (wn + j * 16 + r15) * 32 + kh * 8);
#pragma unroll
    for (int i = 0; i < 4; ++i)
#pragma unroll
      for (int j = 0; j < 4; ++j)
        acc[i][j] = __builtin_amdgcn_mfma_f32_16x16x32_bf16(af[i], bfv[j], acc[i][j], 0, 0, 0);
    __syncthreads();
  }

  if constexpr (EPI == EPI_POOL){
    // stash C tile (bf16) in LDS, then 2x2 spatial maxpool + bias.
    uint16_t* Cp = (uint16_t*)smem;
#pragma unroll
    for (int i = 0; i < 4; ++i)
#pragma unroll
      for (int j = 0; j < 4; ++j)
#pragma unroll
        for (int tt = 0; tt < 4; ++tt){
          int rr = wm + i * 16 + kh * 4 + tt;
          int cc = wn + j * 16 + r15;
          Cp[rr * 128 + cc] = f2bf(acc[i][j][tt]);
        }
    __syncthreads();
    uint16_t* obp = (uint16_t*)outp;
    const int orow0 = blockIdx.x * 32;
#pragma unroll
    for (int e2 = 0; e2 < 16; ++e2){
      int idx = tid + 256 * e2;
      int X = idx >> 7, c = idx & 127;
      int gn = n0 + c;
      if (gn < N){
        float v0 = bflo(Cp[(2 * X) * 128 + c]);
        float v1 = bflo(Cp[(2 * X + 1) * 128 + c]);
        float v2 = bflo(Cp[(64 + 2 * X) * 128 + c]);
        float v3 = bflo(Cp[(65 + 2 * X) * 128 + c]);
        float v = fmaxf(fmaxf(v0, v1), fmaxf(v2, v3)) + bias[gn];
        obp[(size_t)(orow0 + X) * N + gn] = f2bf(v);
      }
    }
  } else if constexpr (EPI == EPI_ADPT){
    // cols 0..63: 0.5*g_e*gelu(h+db); col 64/65: 0.5*g_e; cols 66..95: 0. out stride ldo.
    float* gl = (float*)smem;   // [128][2] gate logits
#pragma unroll
    for (int i = 0; i < 4; ++i)
#pragma unroll
      for (int j = 0; j < 4; ++j){
        int c = wn + j * 16 + r15;
        if (c == 64 || c == 65){
#pragma unroll
          for (int tt = 0; tt < 4; ++tt){
            int rr = wm + i * 16 + kh * 4 + tt;
            gl[rr * 2 + (c - 64)] = acc[i][j][tt] + bias[c];
          }
        }
      }
    __syncthreads();
    uint16_t* op = (uint16_t*)outp;
#pragma unroll
    for (int i = 0; i < 4; ++i)
#pragma unroll
      for (int tt = 0; tt < 4; ++tt){
        int rr = wm + i * 16 + kh * 4 + tt;
        int gm = m0 + rr;
        float l0 = gl[rr * 2], l1 = gl[rr * 2 + 1];
        float mx = fmaxf(l0, l1);
        float e0 = __expf(l0 - mx), e1 = __expf(l1 - mx);
        float inv = 0.5f / (e0 + e1);
#pragma unroll
        for (int j = 0; j < 4; ++j){
          int c = wn + j * 16 + r15;
          if (c < 96){
            float val;
            if (c < 64){
              float g = ((c >> 5) == 0 ? e0 : e1) * inv;
              val = g * geluf(acc[i][j][tt] + bias[c]);
            } else if (c == 64) val = e0 * inv;
            else if (c == 65) val = e1 * inv;
            else val = 0.0f;
            op[(size_t)gm * ldo + c] = f2bf(val);
          }
        }
      }
  } else {
    int coln[4]; float bcol[4];
#pragma unroll
    for (int j = 0; j < 4; ++j){
      coln[j] = n0 + wn + j * 16 + r15;
      bcol[j] = (coln[j] < N) ? bias[coln[j]] : 0.0f;
    }
#pragma unroll
    for (int i = 0; i < 4; ++i)
#pragma unroll
      for (int tt = 0; tt < 4; ++tt){
        const int gm = m0 + wm + i * 16 + kh * 4 + tt;
        const size_t ro = (size_t)gm * ldo;
#pragma unroll
        for (int j = 0; j < 4; ++j){
          if (coln[j] < N){
            float v = acc[i][j][tt] + bcol[j];
            if constexpr (EPI == EPI_KV){
              // n<576: K -> kb[token][576]. n>=576: V -> vt[wh][80][256] transposed.
              int n = coln[j];
              if (n < 576){
                ((uint16_t*)outp)[(size_t)gm * 576 + n] = f2bf(v);
              } else {
                int d = n - 576;
                int hh = d / 72, dd = d - hh * 72;
                int bimg = gm >> 12, y = (gm >> 6) & 63, x = gm & 63;
                int w = bimg * 16 + (y >> 4) * 4 + (x >> 4);
                int kl = (y & 15) * 16 + (x & 15);
                ((uint16_t*)r1)[((size_t)(w * 8 + hh) * 80 + dd) * 256 + kl] = f2bf(v);
              }
            } else if constexpr (EPI == EPI_GELU){
              ((uint16_t*)outp)[ro + coln[j]] = f2bf(geluf(v));
            } else if constexpr (EPI == EPI_ADD1){
              v += bflo(((const uint16_t*)r1)[(size_t)gm * 576 + coln[j]]);
              ((float*)outp)[ro + coln[j]] = v;
              ((uint16_t*)r2)[(size_t)gm * 576 + coln[j]] = f2bf(v);
            } else { // EPI_ADDF
              v += ((const float*)r1)[(size_t)gm * 576 + coln[j]];
              ((float*)outp)[ro + coln[j]] = v;
            }
          }
        }
      }
  }
}

// ---------------- MFMA windowed attention: 1 wave per (window, head) ----------------
__global__ __launch_bounds__(64, 1) void attn_mfma_k(
    const uint16_t* __restrict__ qp,   // [8192][576] pooled q (unscaled)
    const uint16_t* __restrict__ kb,   // [32768][576] K
    const uint16_t* __restrict__ vt,   // [1024][80][256] V^T per (window,head), rows 72..79 zero
    uint16_t* __restrict__ o)          // [8192][576]
{
  const int lane = threadIdx.x;
  const int r15 = lane & 15;
  const int kh = lane >> 4;
  const int bid = blockIdx.x;          // 0..1023
  const int h = bid & 7;
  const int w = bid >> 3;
  const int b = w >> 4;
  const int wy = (w >> 2) & 3;
  const int wx = w & 3;

  const u32x4 ZU = {0, 0, 0, 0};
  const bf16x8 Z8 = __builtin_bit_cast(bf16x8, ZU);
  const float scale = 0.11785113019775793f;  // 1/sqrt(72)

  bf16x8 qf[4][3];
  int qrow[4];
#pragma unroll
  for (int j = 0; j < 4; ++j){
    int q = j * 16 + r15;
    int y = wy * 8 + (q >> 3), x = wx * 8 + (q & 7);
    qrow[j] = b * 1024 + y * 32 + x;
    const uint16_t* qpr = qp + (size_t)qrow[j] * 576 + h * 72;
    qf[j][0] = *(const bf16x8*)(qpr + kh * 8);
    qf[j][1] = *(const bf16x8*)(qpr + 32 + kh * 8);
    qf[j][2] = (kh == 0) ? *(const bf16x8*)(qpr + 64) : Z8;
  }

  float m[4], l[4];
#pragma unroll
  for (int j = 0; j < 4; ++j){ m[j] = -INFINITY; l[j] = 0.0f; }
  f32x4 acco[5][4] = {};
  const size_t vtbase = (size_t)(w * 8 + h) * 80 * 256;

  for (int t = 0; t < 4; ++t){
    f32x4 accs[4][4] = {};
#pragma unroll
    for (int i = 0; i < 4; ++i){
      const uint16_t* kr = kb + (size_t)(b * 4096 + (wy * 16 + t * 4 + i) * 64 + wx * 16 + r15) * 576 + h * 72;
      bf16x8 kf0 = *(const bf16x8*)(kr + kh * 8);
      bf16x8 kf1 = *(const bf16x8*)(kr + 32 + kh * 8);
      bf16x8 kf2 = (kh == 0) ? *(const bf16x8*)(kr + 64) : Z8;
#pragma unroll
      for (int j = 0; j < 4; ++j){
        accs[i][j] = __builtin_amdgcn_mfma_f32_16x16x32_bf16(kf0, qf[j][0], accs[i][j], 0, 0, 0);
        accs[i][j] = __builtin_amdgcn_mfma_f32_16x16x32_bf16(kf1, qf[j][1], accs[i][j], 0, 0, 0);
        accs[i][j] = __builtin_amdgcn_mfma_f32_16x16x32_bf16(kf2, qf[j][2], accs[i][j], 0, 0, 0);
      }
    }
#pragma unroll
    for (int j = 0; j < 4; ++j){
      float mx = -INFINITY;
#pragma unroll
      for (int i = 0; i < 4; ++i)
#pragma unroll
        for (int tt = 0; tt < 4; ++tt){
          float sv = accs[i][j][tt] * scale;
          accs[i][j][tt] = sv;
          mx = fmaxf(mx, sv);
        }
      mx = fmaxf(mx, __shfl_xor(mx, 16));
      mx = fmaxf(mx, __shfl_xor(mx, 32));
      float nm = fmaxf(m[j], mx);
      float f = __expf(m[j] - nm);
      m[j] = nm;
      l[j] *= f;
#pragma unroll
      for (int i2 = 0; i2 < 5; ++i2) acco[i2][j] *= f;
      float ls = 0.0f;
#pragma unroll
      for (int i = 0; i < 4; ++i)
#pragma unroll
        for (int tt = 0; tt < 4; ++tt){
          float p = __expf(accs[i][j][tt] - nm);
          accs[i][j][tt] = p;
          ls += p;
        }
      ls += __shfl_xor(ls, 16);
      ls += __shfl_xor(ls, 32);
      l[j] += ls;
    }
    uint32_t pw[4][4][2];
#pragma unroll
    for (int i = 0; i < 4; ++i)
#pragma unroll
      for (int j = 0; j < 4; ++j){
        pw[i][j][0] = pk2(accs[i][j][0], accs[i][j][1]);
        pw[i][j][1] = pk2(accs[i][j][2], accs[i][j][3]);
      }
#pragma unroll
    for (int ks = 0; ks < 2; ++ks){
      bf16x8 pb[4];
#pragma unroll
      for (int j = 0; j < 4; ++j){
        u32x4 u = {pw[2 * ks][j][0], pw[2 * ks][j][1], pw[2 * ks + 1][j][0], pw[2 * ks + 1][j][1]};
        pb[j] = __builtin_bit_cast(bf16x8, u);
      }
#pragma unroll
      for (int i2 = 0; i2 < 5; ++i2){
        const uint16_t* vr = vt + vtbase + (size_t)(i2 * 16 + r15) * 256 + t * 64 + ks * 32 + kh * 4;
        u32x2 lo = *(const u32x2*)(vr);
        u32x2 hi = *(const u32x2*)(vr + 16);
        u32x4 av = {lo[0], lo[1], hi[0], hi[1]};
        bf16x8 va = __builtin_bit_cast(bf16x8, av);
#pragma unroll
        for (int j = 0; j < 4; ++j)
          acco[i2][j] = __builtin_amdgcn_mfma_f32_16x16x32_bf16(va, pb[j], acco[i2][j], 0, 0, 0);
      }
    }
  }

#pragma unroll
  for (int j = 0; j < 4; ++j){
    float inv = 1.0f / l[j];
    uint16_t* orow = o + (size_t)qrow[j] * 576 + h * 72;
#pragma unroll
    for (int i2 = 0; i2 < 5; ++i2)
#pragma unroll
      for (int tt = 0; tt < 4; ++tt){
        int d = i2 * 16 + kh * 4 + tt;
        if (d < 72) orow[d] = f2bf(acco[i2][j][tt] * inv);
      }
  }
}

extern "C" void kernel_launch(void* const* d_in, const int* in_sizes, int n_in,
                              void* d_out, int out_size, void* d_ws, size_t ws_size,
                              hipStream_t stream)
{
  (void)in_sizes; (void)n_in; (void)out_size; (void)ws_size;
  const float* srcs[2] = { (const float*)d_in[0], (const float*)d_in[1] };
  const float* n1g    = (const float*)d_in[2];
  const float* n1b    = (const float*)d_in[3];
  const float* proj_w = (const float*)d_in[4];
  const float* proj_b = (const float*)d_in[5];
  const float* qkv_w  = (const float*)d_in[6];
  const float* qkv_b  = (const float*)d_in[7];
  const float* ap_w   = (const float*)d_in[8];
  const float* ap_b   = (const float*)d_in[9];
  const float* n2g    = (const float*)d_in[10];
  const float* n2b    = (const float*)d_in[11];
  const float* w1     = (const float*)d_in[12];
  const float* b1     = (const float*)d_in[13];
  const float* w2     = (const float*)d_in[14];
  const float* b2     = (const float*)d_in[15];
  const float* gw     = (const float*)d_in[16];
  const float* gb     = (const float*)d_in[17];
  const float* dwn    = (const float*)d_in[18];
  const float* dbn    = (const float*)d_in[19];
  const float* uw     = (const float*)d_in[20];
  const float* ub     = (const float*)d_in[21];

  char* ws = (char*)d_ws;
  size_t off = 0;
  auto alloc = [&](size_t bytes){ size_t o = off; off += (bytes + 255) & ~(size_t)255; return o; };

  // shared weights (bf16)
  uint16_t* projT = (uint16_t*)(ws + alloc((size_t)640 * 288 * 2));
  uint16_t* qT    = (uint16_t*)(ws + alloc((size_t)640 * 288 * 2));
  uint16_t* kvT   = (uint16_t*)(ws + alloc((size_t)1152 * 288 * 2));
  uint16_t* aT    = (uint16_t*)(ws + alloc((size_t)640 * 576 * 2));
  uint16_t* m1T   = (uint16_t*)(ws + alloc((size_t)2304 * 576 * 2));
  uint16_t* m2Te  = (uint16_t*)(ws + alloc((size_t)2 * 640 * 2400 * 2));  // per-stream extended
  uint16_t* adT   = (uint16_t*)(ws + alloc((size_t)2 * 128 * 576 * 2));
  float*    adB   = (float*)(ws + alloc((size_t)2 * 128 * 4));
  // per-stream activations (reused for si=0,1)
  size_t oXN = alloc((size_t)32768 * 288 * 2);       // xn bf16; later x2 f32 (same bytes)
  uint16_t* xn  = (uint16_t*)(ws + oXN);
  float*    x2  = (float*)(ws + oXN);
  uint16_t* sc  = (uint16_t*)(ws + alloc((size_t)8192 * 576 * 2));   // pooled shortcut bf16
  size_t oQP = alloc((size_t)8192 * 576 * 2);        // qp bf16; later x2b bf16
  uint16_t* qp  = (uint16_t*)(ws + oQP);
  uint16_t* x2b = (uint16_t*)(ws + oQP);
  uint16_t* kb  = (uint16_t*)(ws + alloc((size_t)32768 * 576 * 2));  // K bf16 [32768][576]
  size_t oVT = alloc((size_t)1024 * 80 * 256 * 2);   // V^T bf16; later mlpA [8192][2400] bf16
  uint16_t* vt   = (uint16_t*)(ws + oVT);
  uint16_t* mlpA = (uint16_t*)(ws + oVT);
  size_t oR2 = alloc((size_t)2 * 8192 * 576 * 2);    // ob bf16 @0, hb bf16 @+9.4MB
  uint16_t* ob = (uint16_t*)(ws + oR2);
  uint16_t* hb = (uint16_t*)(ws + oR2 + (size_t)8192 * 576 * 2);

  // weight prep (once)
  wtrans_k<<<(640 * 288 + 255) / 256, 256, 0, stream>>>(proj_w, projT, 288, 576, 640, 576, 0);
  wtrans_k<<<(640 * 288 + 255) / 256, 256, 0, stream>>>(qkv_w, qT, 288, 576, 640, 1728, 0);
  wtrans_k<<<(1152 * 288 + 255) / 256, 256, 0, stream>>>(qkv_w, kvT, 288, 1152, 1152, 1728, 576);
  wtrans_k<<<(640 * 576 + 255) / 256, 256, 0, stream>>>(ap_w, aT, 576, 576, 640, 576, 0);
  wtrans_k<<<(2304 * 576 + 255) / 256, 256, 0, stream>>>(w1, m1T, 576, 2304, 2304, 2304, 0);
  mk_m2te_k<<<(2 * 640 * 2400 + 255) / 256, 256, 0, stream>>>(w2, uw, ub, m2Te);
  mk_adt_k<<<(2 * 128 * 576 + 255) / 256, 256, 0, stream>>>(dwn, gw, dbn, gb, adT, adB);

  for (int si = 0; si < 2; ++si){
    float* outf = (float*)d_out + (size_t)si * 8192 * 576;

    // LN1 -> xn bf16 [32768 x 288]
    ln_k<<<8192, 256, 0, stream>>>(srcs[si], 288, n1g, n1b, xn);

    // zero V^T pad rows (72..79 of each slab)
    vtpad_k<<<(1024 * 8 * 256) / 256, 256, 0, stream>>>(vt);

    // proj + pooled shortcut; pooled q; k,v (K compact + V^T scatter)
    gemm_k<EPI_POOL><<<dim3(256, 5), 256, 0, stream>>>(xn, projT, proj_b, sc, nullptr, nullptr, 576, 288, 576);
    gemm_k<EPI_POOL><<<dim3(256, 5), 256, 0, stream>>>(xn, qT, qkv_b, qp, nullptr, nullptr, 576, 288, 576);
    gemm_k<EPI_KV><<<dim3(256, 9), 256, 0, stream>>>(xn, kvT, qkv_b + 576, kb, vt, nullptr, 1152, 288, 1152);

    // MFMA windowed attention -> ob bf16 [8192 x 576]
    attn_mfma_k<<<1024, 64, 0, stream>>>(qp, kb, vt, ob);

    // attn out-proj + shortcut -> x2 f32 (aliases xn) + x2b bf16 (aliases qp, dead after attn)
    gemm_k<EPI_ADD1><<<dim3(64, 5), 256, 0, stream>>>(ob, aT, ap_b, x2, sc, x2b, 576, 576, 576);

    // LN2 -> hb bf16
    ln_k<<<2048, 256, 0, stream>>>(x2, 576, n2g, n2b, hb);

    // MLP up + gelu -> mlpA cols 0..2303 (ld 2400; aliases vt, dead after attn)
    gemm_k<EPI_GELU><<<dim3(64, 18), 256, 0, stream>>>(hb, m1T, b1, mlpA, nullptr, nullptr, 2304, 576, 2400);

    // adapter phase-1: gate+down+gelu -> mlpA cols 2304..2399
    gemm_k<EPI_ADPT><<<dim3(64, 1), 256, 0, stream>>>(x2b, adT + (size_t)si * 128 * 576, adB + si * 128,
                                                      mlpA + 2304, nullptr, nullptr, 128, 576, 2400);

    // MLP down + adapter up + x2 -> out f32 (K=2400 extended)
    gemm_k<EPI_ADDF><<<dim3(64, 5), 256, 0, stream>>>(mlpA, m2Te + (size_t)si * 640 * 2400, b2, outf,
                                                      x2, nullptr, 576, 2400, 576);
  }
}